// Round 3
// baseline (14.783 us; speedup 1.0000x reference)
//
#include <hip/hip_runtime.h>

#define GRAN 256
#define BATCH 4096

// 256-thread blocks, 4 batches per block, one wave per batch.
// All per-batch state is wave-uniform -> scalar loads; no LDS, no barriers.
//
// Padded gt rows (npoly < 8) are zeros: d2[i][j] = |y_j|^2 exactly, so
// row-min = min_j y2[j] (constant) and colmin[j] starts at y2[j].
// Rotation periodicity: n=4 -> 64 distinct rotations, n=8 -> 32.
template<int NPOLY, int NROT>
__device__ __forceinline__ float chamfer_min(const float* __restrict__ yb,
                                             const float* __restrict__ ex,
                                             int lane) {
    float yx[8], yv[8];
#pragma unroll
    for (int j = 0; j < 8; ++j) { yx[j] = yb[2 * j]; yv[j] = yb[2 * j + 1]; }

    float y2[8];
#pragma unroll
    for (int j = 0; j < 8; ++j) y2[j] = yx[j] * yx[j] + yv[j] * yv[j];
    float miny2 = y2[0];
#pragma unroll
    for (int j = 1; j < 8; ++j) miny2 = fminf(miny2, y2[j]);

    float best = 1e30f;
    constexpr int KMAX = (NROT + 63) / 64;
#pragma unroll 2
    for (int k = 0; k < KMAX; ++k) {
        if (NROT >= 64 || lane < NROT) {
            const int r = lane + 64 * k;
            const float4* g4 = (const float4*)(ex + (size_t)r * 16);
            constexpr int NL = (NPOLY + 1) / 2;
            float4 buf[NL];
#pragma unroll
            for (int t = 0; t < NL; ++t) buf[t] = g4[t];
            float gx[NPOLY], gy[NPOLY];
#pragma unroll
            for (int i = 0; i < NPOLY; ++i) {
                gx[i] = (i & 1) ? buf[i >> 1].z : buf[i >> 1].x;
                gy[i] = (i & 1) ? buf[i >> 1].w : buf[i >> 1].y;
            }

            float colmin[8];
#pragma unroll
            for (int j = 0; j < 8; ++j) colmin[j] = (NPOLY < 8) ? y2[j] : 1e30f;
            float rowsum = (NPOLY < 8) ? (float)(8 - NPOLY) * miny2 : 0.0f;

#pragma unroll
            for (int i = 0; i < NPOLY; ++i) {
                float rmin = 1e30f;
#pragma unroll
                for (int j = 0; j < 8; ++j) {
                    float dx = gx[i] - yx[j];
                    float dy = gy[i] - yv[j];
                    float d = dx * dx + dy * dy;
                    rmin = fminf(rmin, d);
                    colmin[j] = fminf(colmin[j], d);
                }
                rowsum += rmin;
            }
            float colsum = colmin[0];
#pragma unroll
            for (int j = 1; j < 8; ++j) colsum += colmin[j];

            best = fminf(best, (rowsum + colsum) * 0.125f);
        }
    }

#pragma unroll
    for (int off = 32; off >= 1; off >>= 1)
        best = fminf(best, __shfl_xor(best, off, 64));
    return best;
}

__global__ __launch_bounds__(256) void rotated_polygon_loss_kernel(
        const float* __restrict__ y,        // [B, 8, 2]
        const int* __restrict__ n,          // [B]
        const float* __restrict__ examples, // [6, 256, 8, 2]
        float* __restrict__ out) {          // [B]
    const int b = blockIdx.x * 4 + (threadIdx.x >> 6);  // wave -> batch
    const int lane = threadIdx.x & 63;

    const int idx = n[b] - 3;  // labels are exactly [3..8]
    const float* yb = y + (size_t)b * 16;
    const float* ex = examples + (size_t)idx * GRAN * 16;

    float best;
    switch (idx) {
        case 0: best = chamfer_min<3, 256>(yb, ex, lane); break;
        case 1: best = chamfer_min<4,  64>(yb, ex, lane); break;
        case 2: best = chamfer_min<5, 256>(yb, ex, lane); break;
        case 3: best = chamfer_min<6, 256>(yb, ex, lane); break;
        case 4: best = chamfer_min<7, 256>(yb, ex, lane); break;
        default: best = chamfer_min<8, 32>(yb, ex, lane); break;
    }

    if (lane == 0) out[b] = best;
}

extern "C" void kernel_launch(void* const* d_in, const int* in_sizes, int n_in,
                              void* d_out, int out_size, void* d_ws, size_t ws_size,
                              hipStream_t stream) {
    const float* y        = (const float*)d_in[0];
    const int*   n        = (const int*)d_in[1];
    // d_in[2] = labels (unused: labels are exactly [3..8])
    const float* examples = (const float*)d_in[3];
    float* out = (float*)d_out;

    rotated_polygon_loss_kernel<<<BATCH / 4, 256, 0, stream>>>(y, n, examples, out);
}

// Round 4
// 12.656 us; speedup vs baseline: 1.1680x; 1.1680x over previous
//
#include <hip/hip_runtime.h>

#define GRAN 256
#define BATCH 4096

// One wave (64 threads) per batch element. Lane L handles rotations
// L, L+64, L+128, L+192 (fewer when the template is rotation-periodic:
// n=8 -> 32 distinct rotations, n=4 -> 64).
//
// Padded gt rows (npoly < 8) are zeros: d2[i][j] = |y_j|^2 exactly, so
// row-min = min_j y2[j] (constant) and colmin[j] starts at y2[j].
//
// NOTE (R2 post-mortem): measured dur_us ~12.8 is ~11 us single-launch
// graph-replay floor + ~1.5 us kernel; grid-shape and work-count changes
// are invisible below the floor. This config was the best measured.
template<int NPOLY, int NROT>
__device__ __forceinline__ float chamfer_min(const float* __restrict__ yb,
                                             const float* __restrict__ ex,
                                             int lane) {
    // y[b]: 16 floats, wave-uniform address -> scalar loads
    float yx[8], yv[8];
#pragma unroll
    for (int j = 0; j < 8; ++j) { yx[j] = yb[2 * j]; yv[j] = yb[2 * j + 1]; }

    float y2[8];
#pragma unroll
    for (int j = 0; j < 8; ++j) y2[j] = yx[j] * yx[j] + yv[j] * yv[j];
    float miny2 = y2[0];
#pragma unroll
    for (int j = 1; j < 8; ++j) miny2 = fminf(miny2, y2[j]);

    float best = 1e30f;
    constexpr int KMAX = (NROT + 63) / 64;
#pragma unroll 2
    for (int k = 0; k < KMAX; ++k) {
        if (NROT >= 64 || lane < NROT) {
            const int r = lane + 64 * k;
            const float4* g4 = (const float4*)(ex + (size_t)r * 16);
            constexpr int NL = (NPOLY + 1) / 2;
            float4 buf[NL];
#pragma unroll
            for (int t = 0; t < NL; ++t) buf[t] = g4[t];
            float gx[NPOLY], gy[NPOLY];
#pragma unroll
            for (int i = 0; i < NPOLY; ++i) {
                gx[i] = (i & 1) ? buf[i >> 1].z : buf[i >> 1].x;
                gy[i] = (i & 1) ? buf[i >> 1].w : buf[i >> 1].y;
            }

            float colmin[8];
#pragma unroll
            for (int j = 0; j < 8; ++j) colmin[j] = (NPOLY < 8) ? y2[j] : 1e30f;
            float rowsum = (NPOLY < 8) ? (float)(8 - NPOLY) * miny2 : 0.0f;

#pragma unroll
            for (int i = 0; i < NPOLY; ++i) {
                float rmin = 1e30f;
#pragma unroll
                for (int j = 0; j < 8; ++j) {
                    float dx = gx[i] - yx[j];
                    float dy = gy[i] - yv[j];
                    float d = dx * dx + dy * dy;
                    rmin = fminf(rmin, d);
                    colmin[j] = fminf(colmin[j], d);
                }
                rowsum += rmin;
            }
            float colsum = colmin[0];
#pragma unroll
            for (int j = 1; j < 8; ++j) colsum += colmin[j];

            best = fminf(best, (rowsum + colsum) * 0.125f);
        }
    }

    // in-wave min reduction (64 lanes)
#pragma unroll
    for (int off = 32; off >= 1; off >>= 1)
        best = fminf(best, __shfl_xor(best, off, 64));
    return best;
}

__global__ __launch_bounds__(64) void rotated_polygon_loss_kernel(
        const float* __restrict__ y,        // [B, 8, 2]
        const int* __restrict__ n,          // [B]
        const float* __restrict__ examples, // [6, 256, 8, 2]
        float* __restrict__ out) {          // [B]
    const int b = blockIdx.x;
    const int lane = threadIdx.x;

    const int idx = n[b] - 3;  // labels are exactly [3..8]
    const float* yb = y + (size_t)b * 16;
    const float* ex = examples + (size_t)idx * GRAN * 16;

    float best;
    switch (idx) {
        case 0: best = chamfer_min<3, 256>(yb, ex, lane); break;
        case 1: best = chamfer_min<4,  64>(yb, ex, lane); break;  // period 2pi/4
        case 2: best = chamfer_min<5, 256>(yb, ex, lane); break;
        case 3: best = chamfer_min<6, 256>(yb, ex, lane); break;
        case 4: best = chamfer_min<7, 256>(yb, ex, lane); break;
        default: best = chamfer_min<8, 32>(yb, ex, lane); break;  // period 2pi/8
    }

    if (lane == 0) out[b] = best;
}

extern "C" void kernel_launch(void* const* d_in, const int* in_sizes, int n_in,
                              void* d_out, int out_size, void* d_ws, size_t ws_size,
                              hipStream_t stream) {
    const float* y        = (const float*)d_in[0];
    const int*   n        = (const int*)d_in[1];
    // d_in[2] = labels (unused: labels are exactly [3..8])
    const float* examples = (const float*)d_in[3];
    float* out = (float*)d_out;

    rotated_polygon_loss_kernel<<<BATCH, 64, 0, stream>>>(y, n, examples, out);
}